// Round 21
// baseline (172.728 us; speedup 1.0000x reference)
//
#include <hip/hip_runtime.h>

// B=4, S=2048, H=1024, NH=16, HD=64. BH = B*NH = 64 flattened heads.
// ws layout (bytes):
//   Xb  @ 0        : 8192*1024*2  = 16 MiB   (X as bf16, row-major [8192][1024])
//   Wt  @ 16 MiB   : 3*1024*1024*2 = 6 MiB   (W transposed+bf16: [qkv][n][k])
//   Q   @ 22 MiB   : [64][2048][64] bf16 (pre-scaled by 0.125*log2e)
//   K   @ 38 MiB   : [64][2048][64] bf16
//   Vt  @ 54 MiB   : [64][64][2048] bf16 (V transposed per head)
// total 70 MiB

typedef __bf16 bf16x8 __attribute__((ext_vector_type(8)));
typedef __bf16 bf16x4 __attribute__((ext_vector_type(4)));
typedef float f32x4 __attribute__((ext_vector_type(4)));
typedef unsigned short ushort8 __attribute__((ext_vector_type(8)));

#define MFMA16(a, b, c) __builtin_amdgcn_mfma_f32_16x16x32_bf16(a, b, c, 0, 0, 0)

static __device__ __forceinline__ unsigned short f2bf(float x) {
    unsigned int u = __float_as_uint(x);
    u = u + 0x7fffu + ((u >> 16) & 1u);   // round-to-nearest-even
    return (unsigned short)(u >> 16);
}

static __device__ __forceinline__ void gload_lds16(const void* g, void* l) {
    __builtin_amdgcn_global_load_lds(
        (const __attribute__((address_space(1))) unsigned int*)g,
        (__attribute__((address_space(3))) unsigned int*)l,
        16, 0, 0);
}

// ---------------- pass 0a: X f32 -> bf16 ----------------
__global__ void convert_x(const float* __restrict__ x, unsigned short* __restrict__ y) {
    size_t i = ((size_t)blockIdx.x * 256 + threadIdx.x) * 8;
    float4 a = *(const float4*)(x + i);
    float4 b = *(const float4*)(x + i + 4);
    ushort8 o;
    o[0] = f2bf(a.x); o[1] = f2bf(a.y); o[2] = f2bf(a.z); o[3] = f2bf(a.w);
    o[4] = f2bf(b.x); o[5] = f2bf(b.y); o[6] = f2bf(b.z); o[7] = f2bf(b.w);
    *(ushort8*)(y + i) = o;
}

// ---------------- pass 0b: W [k][n] f32 -> Wt [n][k] bf16 ----------------
__global__ void wtrans(const float* __restrict__ Wq, const float* __restrict__ Wk,
                       const float* __restrict__ Wv, unsigned short* __restrict__ Wt) {
    __shared__ float T[64][68];
    const float* W = blockIdx.z == 0 ? Wq : (blockIdx.z == 1 ? Wk : Wv);
    int k0 = blockIdx.y * 64, n0 = blockIdx.x * 64;
    int t = threadIdx.x;
    int rr = t >> 2, c4 = (t & 3) * 16;
    for (int j = 0; j < 16; j += 4) {
        float4 v = *(const float4*)(W + (size_t)(k0 + rr) * 1024 + n0 + c4 + j);
        T[rr][c4 + j] = v.x; T[rr][c4 + j + 1] = v.y;
        T[rr][c4 + j + 2] = v.z; T[rr][c4 + j + 3] = v.w;
    }
    __syncthreads();
    unsigned short* o = Wt + ((size_t)blockIdx.z << 20) + (size_t)(n0 + rr) * 1024 + k0 + c4;
    for (int j = 0; j < 16; j += 8) {
        ushort8 v;
        for (int u = 0; u < 8; u++) v[u] = f2bf(T[c4 + j + u][rr]);
        *(ushort8*)(o + j) = v;
    }
}

// ---------------- pass 1: fused QKV GEMM (BK=64, swizzled LDS — R18 verified) ----
__global__ __launch_bounds__(256, 2) void qkv_gemm(
    const unsigned short* __restrict__ Xb, const unsigned short* __restrict__ Wt,
    const float* __restrict__ bq, const float* __restrict__ bk, const float* __restrict__ bv,
    unsigned short* __restrict__ Q, unsigned short* __restrict__ K,
    unsigned short* __restrict__ Vt) {
    __shared__ __align__(16) unsigned char smem[65536];  // A: 2x16K @0, B: 2x16K @32K

    int tid = threadIdx.x;
    int wave = tid >> 6, lane = tid & 63;
    int g = lane >> 4, r = lane & 15;
    // T1 XCD swizzle: nwg = 24*64 = 1536, 192 contiguous per XCD (bijective)
    int f = blockIdx.x + blockIdx.y * 24;
    int nf = (f & 7) * 192 + (f >> 3);
    int bx = nf % 24, by = nf / 24;
    int m0 = by * 128;
    int col0 = bx * 128;
    int qkv = col0 >> 10;
    int ncol0 = col0 & 1023;
    int wr = wave >> 1, wc = wave & 1;
    const unsigned short* Wb = Wt + ((size_t)qkv << 20);

    auto stage = [&](int buf, int k0) {
#pragma unroll
        for (int i = 0; i < 4; i++) {
            int slot = (i * 4 + wave) * 64 + lane;
            int row = slot >> 3;                       // 128B rows, 8 chunks each
            int ch = (slot & 7) ^ (row & 7);
            gload_lds16(Xb + (size_t)(m0 + row) * 1024 + k0 + ch * 8,
                        smem + buf * 16384 + (i * 4 + wave) * 1024);
            gload_lds16(Wb + (size_t)(ncol0 + row) * 1024 + k0 + ch * 8,
                        smem + 32768 + buf * 16384 + (i * 4 + wave) * 1024);
        }
    };

    f32x4 acc[4][4];
    for (int m = 0; m < 4; m++)
        for (int n = 0; n < 4; n++)
            for (int u = 0; u < 4; u++) acc[m][n][u] = 0.f;

    stage(0, 0);
    __syncthreads();
    int buf = 0;
    for (int t = 0; t < 16; ++t) {
        if (t < 15) stage(buf ^ 1, (t + 1) * 64);
        const unsigned char* Ab = smem + buf * 16384;
        const unsigned char* Bb = smem + 32768 + buf * 16384;
#pragma unroll
        for (int kk = 0; kk < 2; kk++) {
            bf16x8 af[4], bfv[4];
#pragma unroll
            for (int m = 0; m < 4; m++) {
                int row = wr * 64 + m * 16 + r;
                af[m] = *(const bf16x8*)(Ab + row * 128 + ((((kk * 4 + g) << 4)) ^ ((row & 7) << 4)));
            }
#pragma unroll
            for (int n = 0; n < 4; n++) {
                int row = wc * 64 + n * 16 + r;
                bfv[n] = *(const bf16x8*)(Bb + row * 128 + ((((kk * 4 + g) << 4)) ^ ((row & 7) << 4)));
            }
#pragma unroll
            for (int m = 0; m < 4; m++)
#pragma unroll
                for (int n = 0; n < 4; n++)
                    acc[m][n] = MFMA16(af[m], bfv[n], acc[m][n]);
        }
        __syncthreads();   // drains vmcnt (next-tile stage) + lgkm; swap buffers
        buf ^= 1;
    }

    if (qkv != 2) {
        const float* bias = (qkv == 0) ? bq : bk;
        unsigned short* dst = (qkv == 0) ? Q : K;
        float scale = (qkv == 0) ? 0.18033688011112042f : 1.0f;
        for (int m = 0; m < 4; m++)
            for (int n = 0; n < 4; n++) {
                int C = ncol0 + wc * 64 + n * 16 + r;
                int h = C >> 6, d = C & 63;
                float bb = bias[C];
                for (int reg = 0; reg < 4; reg++) {
                    int R = m0 + wr * 64 + m * 16 + 4 * g + reg;
                    int b = R >> 11, s = R & 2047;
                    float val = (acc[m][n][reg] + bb) * scale;
                    dst[((((size_t)b * 16 + h) * 2048) + s) * 64 + d] = f2bf(val);
                }
            }
    } else {
        unsigned short* T = (unsigned short*)smem;  // [128][136]
        for (int m = 0; m < 4; m++)
            for (int n = 0; n < 4; n++) {
                int Cl = wc * 64 + n * 16 + r;
                float bb = bv[ncol0 + Cl];
                for (int reg = 0; reg < 4; reg++) {
                    int Rl = wr * 64 + m * 16 + 4 * g + reg;
                    T[Rl * 136 + Cl] = f2bf(acc[m][n][reg] + bb);
                }
            }
        __syncthreads();
        int dl = tid >> 1, s0c = (tid & 1) * 64;
        int Cg = ncol0 + dl;
        int h = Cg >> 6, dd = Cg & 63;
        int bidx = m0 >> 11;
        int sbase = (m0 & 2047) + s0c;
        unsigned short* dstp = Vt + (((size_t)bidx * 16 + h) * 64 + dd) * 2048 + sbase;
        for (int jc = 0; jc < 8; jc++) {
            ushort8 v;
            for (int u = 0; u < 8; u++) v[u] = T[(s0c + jc * 8 + u) * 136 + dl];
            *(ushort8*)(dstp + jc * 8) = v;
        }
    }
}

// ---------------- pass 2: flash attention (R19 + joint PV over both qi) ----------
// R19 structure (verified 84.7 us) with ONE change: both qi's P packed into a
// [32][64] buffer first, then a single PV pass loads each V fragment ONCE and
// feeds both qi's MFMAs (V ds_reads halved 16->8 per tile/wave; qi0's P read now
// sits behind qi1's pack -> write->read latency hidden). No-max softmax,
// ones-MFMA denominator, T2/G21 swizzles, XCD swizzle, T5 setprio.
// Grid MUST be (16,64).
__global__ __launch_bounds__(256, 4) void attn(
    const unsigned short* __restrict__ Q, const unsigned short* __restrict__ K,
    const unsigned short* __restrict__ Vt, float* __restrict__ out) {
    // LDS: K 2x8K @0, V 2x8K @16K, P [4][32][64] ushort @32K  (total 48 KiB)
    __shared__ __align__(16) unsigned char lds[49152];

    int tid = threadIdx.x, w = tid >> 6, lane = tid & 63;
    int r = lane & 15, g = lane >> 4;
    // T1 XCD swizzle: 1024 blocks, 8 XCDs, 128 contiguous per XCD
    int f = blockIdx.x + (blockIdx.y << 4);
    int nf = ((f & 7) << 7) | (f >> 3);
    int qt = nf & 15, bh = nf >> 4;
    int q0 = qt * 128 + w * 32;
    const unsigned short* Qb = Q + (size_t)bh * 2048 * 64;
    const unsigned short* Kb = K + (size_t)bh * 2048 * 64;
    const unsigned short* Vb = Vt + (size_t)bh * 64 * 2048;

    // stage K tile [64 kv][64 d] and V tile [64 d][64 kv], pre-swizzled source
    auto stageKV = [&](int buf, int kv0) {
#pragma unroll
        for (int i = 0; i < 2; i++) {
            int slot = (i * 4 + w) * 64 + lane;
            int row = slot >> 3;
            int ch = (slot & 7) ^ (row & 7);
            gload_lds16(Kb + (size_t)(kv0 + row) * 64 + ch * 8,
                        lds + buf * 8192 + (i * 4 + w) * 1024);
            gload_lds16(Vb + (size_t)row * 2048 + kv0 + ch * 8,
                        lds + 16384 + buf * 8192 + (i * 4 + w) * 1024);
        }
    };

    // Q^T B-frags (loaded once from global)
    bf16x8 qf[2][2];
#pragma unroll
    for (int qi = 0; qi < 2; qi++)
#pragma unroll
        for (int sl = 0; sl < 2; sl++)
            qf[qi][sl] = *(const bf16x8*)(Qb + (size_t)(q0 + qi * 16 + r) * 64 + sl * 32 + g * 8);

    // all-ones A-frag for row-sum MFMA
    bf16x8 ones8;
#pragma unroll
    for (int i = 0; i < 8; i++) ones8[i] = (__bf16)1.0f;

    f32x4 o[2][4], ls[2];
#pragma unroll
    for (int qi = 0; qi < 2; qi++) {
#pragma unroll
        for (int u = 0; u < 4; u++) ls[qi][u] = 0.f;
#pragma unroll
        for (int d = 0; d < 4; d++)
#pragma unroll
            for (int u = 0; u < 4; u++) o[qi][d][u] = 0.f;
    }

    stageKV(0, 0);
    __syncthreads();
    int buf = 0;
    int rsw = (r & 7) << 4;  // read/write-side XOR (byte units)
    unsigned char* Pw = lds + 32768 + w * 4096;  // [32][64] ushort, swizzled

    for (int t = 0; t < 32; ++t) {
        if (t < 31) stageKV(buf ^ 1, (t + 1) * 64);
        const unsigned char* Kl = lds + buf * 8192;
        const unsigned char* Vl = lds + 16384 + buf * 8192;

        // ---- joint QK: S^T = K . Q^T for BOTH qi (K read once) ----
        f32x4 s[2][4];
#pragma unroll
        for (int qi = 0; qi < 2; qi++)
#pragma unroll
            for (int kvt = 0; kvt < 4; kvt++)
#pragma unroll
                for (int u = 0; u < 4; u++) s[qi][kvt][u] = 0.f;
        __builtin_amdgcn_s_setprio(1);
#pragma unroll
        for (int kvt = 0; kvt < 4; kvt++) {
            const unsigned char* kp = Kl + (kvt * 16 + r) * 128;
            bf16x8 k0 = *(const bf16x8*)(kp + ((g << 4) ^ rsw));
            bf16x8 k1 = *(const bf16x8*)(kp + (((4 + g) << 4) ^ rsw));
            s[0][kvt] = MFMA16(k0, qf[0][0], s[0][kvt]);
            s[0][kvt] = MFMA16(k1, qf[0][1], s[0][kvt]);
            s[1][kvt] = MFMA16(k0, qf[1][0], s[1][kvt]);
            s[1][kvt] = MFMA16(k1, qf[1][1], s[1][kvt]);
        }
        __builtin_amdgcn_s_setprio(0);

        // ---- exp2 (no max) + pack BOTH qi -> P[32][64] ----
#pragma unroll
        for (int qi = 0; qi < 2; qi++)
#pragma unroll
            for (int kvt = 0; kvt < 4; kvt++) {
                bf16x4 pw;
                pw[0] = (__bf16)__builtin_amdgcn_exp2f(s[qi][kvt][0]);
                pw[1] = (__bf16)__builtin_amdgcn_exp2f(s[qi][kvt][1]);
                pw[2] = (__bf16)__builtin_amdgcn_exp2f(s[qi][kvt][2]);
                pw[3] = (__bf16)__builtin_amdgcn_exp2f(s[qi][kvt][3]);
                *(bf16x4*)(Pw + ((qi * 16 + r) << 7) + ((kvt * 32 + g * 8) ^ rsw)) = pw;
            }

        // ---- joint PV: each V frag loaded once, feeds both qi ----
        __builtin_amdgcn_s_setprio(1);
#pragma unroll
        for (int ks2 = 0; ks2 < 2; ks2++) {
            bf16x8 pf0 = *(const bf16x8*)(Pw + (r << 7) + ((ks2 * 64 + g * 16) ^ rsw));
            bf16x8 pf1 = *(const bf16x8*)(Pw + ((16 + r) << 7) + ((ks2 * 64 + g * 16) ^ rsw));
            ls[0] = MFMA16(ones8, pf0, ls[0]);
            ls[1] = MFMA16(ones8, pf1, ls[1]);
#pragma unroll
            for (int d = 0; d < 4; d++) {
                bf16x8 vf = *(const bf16x8*)(Vl + (d * 16 + r) * 128 + (((ks2 * 4 + g) << 4) ^ rsw));
                o[0][d] = MFMA16(vf, pf0, o[0][d]);
                o[1][d] = MFMA16(vf, pf1, o[1][d]);
            }
        }
        __builtin_amdgcn_s_setprio(0);

        __syncthreads();   // drains vmcnt (next-tile stage) + lgkm; swap buffers
        buf ^= 1;
    }

    // ---- epilogue: O^T[d][q] / l -> out[b][s][h*64+d] ----
    int b = bh >> 4, h = bh & 15;
#pragma unroll
    for (int qi = 0; qi < 2; qi++) {
        float inv = 1.0f / ls[qi][0];
        float* ob = out + ((size_t)b * 2048 + q0 + qi * 16 + r) * 1024 + h * 64;
#pragma unroll
        for (int d = 0; d < 4; d++) {
            float4 v;
            v.x = o[qi][d][0] * inv; v.y = o[qi][d][1] * inv;
            v.z = o[qi][d][2] * inv; v.w = o[qi][d][3] * inv;
            *(float4*)(ob + d * 16 + 4 * g) = v;
        }
    }
}

extern "C" void kernel_launch(void* const* d_in, const int* in_sizes, int n_in,
                              void* d_out, int out_size, void* d_ws, size_t ws_size,
                              hipStream_t stream) {
    const float* X  = (const float*)d_in[0];
    const float* Wq = (const float*)d_in[1];
    const float* bq = (const float*)d_in[2];
    const float* Wk = (const float*)d_in[3];
    const float* bk = (const float*)d_in[4];
    const float* Wv = (const float*)d_in[5];
    const float* bv = (const float*)d_in[6];
    float* out = (float*)d_out;
    char* ws = (char*)d_ws;

    unsigned short* Xb  = (unsigned short*)(ws);
    unsigned short* Wt  = (unsigned short*)(ws + 16777216);
    unsigned short* Qw  = (unsigned short*)(ws + 23068672);
    unsigned short* Kw  = (unsigned short*)(ws + 39845888);
    unsigned short* Vtw = (unsigned short*)(ws + 56623104);

    hipLaunchKernelGGL(convert_x, dim3(4096), dim3(256), 0, stream, X, Xb);
    hipLaunchKernelGGL(wtrans, dim3(16, 16, 3), dim3(256), 0, stream, Wq, Wk, Wv, Wt);
    hipLaunchKernelGGL(qkv_gemm, dim3(24, 64), dim3(256), 0, stream,
                       Xb, Wt, bq, bk, bv, Qw, Kw, Vtw);
    hipLaunchKernelGGL(attn, dim3(16, 64), dim3(256), 0, stream, Qw, Kw, Vtw, out);
}

// Round 22
// 152.553 us; speedup vs baseline: 1.1322x; 1.1322x over previous
//
#include <hip/hip_runtime.h>

// B=4, S=2048, H=1024, NH=16, HD=64. BH = B*NH = 64 flattened heads.
// ws layout (bytes):
//   Xb  @ 0        : 8192*1024*2  = 16 MiB   (X as bf16, row-major [8192][1024])
//   Wt  @ 16 MiB   : 3*1024*1024*2 = 6 MiB   (W transposed+bf16: [qkv][n][k])
//   Q   @ 22 MiB   : [64][2048][64] bf16 (pre-scaled by 0.125*log2e)
//   K   @ 38 MiB   : [64][2048][64] bf16
//   Vt  @ 54 MiB   : [64][64][2048] bf16 (V transposed per head)
// total 70 MiB

typedef __bf16 bf16x8 __attribute__((ext_vector_type(8)));
typedef __bf16 bf16x4 __attribute__((ext_vector_type(4)));
typedef float f32x4 __attribute__((ext_vector_type(4)));
typedef unsigned short ushort8 __attribute__((ext_vector_type(8)));

#define MFMA16(a, b, c) __builtin_amdgcn_mfma_f32_16x16x32_bf16(a, b, c, 0, 0, 0)

static __device__ __forceinline__ unsigned short f2bf(float x) {
    unsigned int u = __float_as_uint(x);
    u = u + 0x7fffu + ((u >> 16) & 1u);   // round-to-nearest-even
    return (unsigned short)(u >> 16);
}

static __device__ __forceinline__ void gload_lds16(const void* g, void* l) {
    __builtin_amdgcn_global_load_lds(
        (const __attribute__((address_space(1))) unsigned int*)g,
        (__attribute__((address_space(3))) unsigned int*)l,
        16, 0, 0);
}

// ---------------- pass 0a: X f32 -> bf16 ----------------
__global__ void convert_x(const float* __restrict__ x, unsigned short* __restrict__ y) {
    size_t i = ((size_t)blockIdx.x * 256 + threadIdx.x) * 8;
    float4 a = *(const float4*)(x + i);
    float4 b = *(const float4*)(x + i + 4);
    ushort8 o;
    o[0] = f2bf(a.x); o[1] = f2bf(a.y); o[2] = f2bf(a.z); o[3] = f2bf(a.w);
    o[4] = f2bf(b.x); o[5] = f2bf(b.y); o[6] = f2bf(b.z); o[7] = f2bf(b.w);
    *(ushort8*)(y + i) = o;
}

// ---------------- pass 0b: W [k][n] f32 -> Wt [n][k] bf16 ----------------
__global__ void wtrans(const float* __restrict__ Wq, const float* __restrict__ Wk,
                       const float* __restrict__ Wv, unsigned short* __restrict__ Wt) {
    __shared__ float T[64][68];
    const float* W = blockIdx.z == 0 ? Wq : (blockIdx.z == 1 ? Wk : Wv);
    int k0 = blockIdx.y * 64, n0 = blockIdx.x * 64;
    int t = threadIdx.x;
    int rr = t >> 2, c4 = (t & 3) * 16;
    for (int j = 0; j < 16; j += 4) {
        float4 v = *(const float4*)(W + (size_t)(k0 + rr) * 1024 + n0 + c4 + j);
        T[rr][c4 + j] = v.x; T[rr][c4 + j + 1] = v.y;
        T[rr][c4 + j + 2] = v.z; T[rr][c4 + j + 3] = v.w;
    }
    __syncthreads();
    unsigned short* o = Wt + ((size_t)blockIdx.z << 20) + (size_t)(n0 + rr) * 1024 + k0 + c4;
    for (int j = 0; j < 16; j += 8) {
        ushort8 v;
        for (int u = 0; u < 8; u++) v[u] = f2bf(T[c4 + j + u][rr]);
        *(ushort8*)(o + j) = v;
    }
}

// ---------------- pass 1: fused QKV GEMM (BK=64, swizzled LDS — R18 verified) ----
__global__ __launch_bounds__(256, 2) void qkv_gemm(
    const unsigned short* __restrict__ Xb, const unsigned short* __restrict__ Wt,
    const float* __restrict__ bq, const float* __restrict__ bk, const float* __restrict__ bv,
    unsigned short* __restrict__ Q, unsigned short* __restrict__ K,
    unsigned short* __restrict__ Vt) {
    __shared__ __align__(16) unsigned char smem[65536];  // A: 2x16K @0, B: 2x16K @32K

    int tid = threadIdx.x;
    int wave = tid >> 6, lane = tid & 63;
    int g = lane >> 4, r = lane & 15;
    // T1 XCD swizzle: nwg = 24*64 = 1536, 192 contiguous per XCD (bijective)
    int f = blockIdx.x + blockIdx.y * 24;
    int nf = (f & 7) * 192 + (f >> 3);
    int bx = nf % 24, by = nf / 24;
    int m0 = by * 128;
    int col0 = bx * 128;
    int qkv = col0 >> 10;
    int ncol0 = col0 & 1023;
    int wr = wave >> 1, wc = wave & 1;
    const unsigned short* Wb = Wt + ((size_t)qkv << 20);

    auto stage = [&](int buf, int k0) {
#pragma unroll
        for (int i = 0; i < 4; i++) {
            int slot = (i * 4 + wave) * 64 + lane;
            int row = slot >> 3;                       // 128B rows, 8 chunks each
            int ch = (slot & 7) ^ (row & 7);
            gload_lds16(Xb + (size_t)(m0 + row) * 1024 + k0 + ch * 8,
                        smem + buf * 16384 + (i * 4 + wave) * 1024);
            gload_lds16(Wb + (size_t)(ncol0 + row) * 1024 + k0 + ch * 8,
                        smem + 32768 + buf * 16384 + (i * 4 + wave) * 1024);
        }
    };

    f32x4 acc[4][4];
    for (int m = 0; m < 4; m++)
        for (int n = 0; n < 4; n++)
            for (int u = 0; u < 4; u++) acc[m][n][u] = 0.f;

    stage(0, 0);
    __syncthreads();
    int buf = 0;
    for (int t = 0; t < 16; ++t) {
        if (t < 15) stage(buf ^ 1, (t + 1) * 64);
        const unsigned char* Ab = smem + buf * 16384;
        const unsigned char* Bb = smem + 32768 + buf * 16384;
#pragma unroll
        for (int kk = 0; kk < 2; kk++) {
            bf16x8 af[4], bfv[4];
#pragma unroll
            for (int m = 0; m < 4; m++) {
                int row = wr * 64 + m * 16 + r;
                af[m] = *(const bf16x8*)(Ab + row * 128 + ((((kk * 4 + g) << 4)) ^ ((row & 7) << 4)));
            }
#pragma unroll
            for (int n = 0; n < 4; n++) {
                int row = wc * 64 + n * 16 + r;
                bfv[n] = *(const bf16x8*)(Bb + row * 128 + ((((kk * 4 + g) << 4)) ^ ((row & 7) << 4)));
            }
#pragma unroll
            for (int m = 0; m < 4; m++)
#pragma unroll
                for (int n = 0; n < 4; n++)
                    acc[m][n] = MFMA16(af[m], bfv[n], acc[m][n]);
        }
        __syncthreads();   // drains vmcnt (next-tile stage) + lgkm; swap buffers
        buf ^= 1;
    }

    if (qkv != 2) {
        const float* bias = (qkv == 0) ? bq : bk;
        unsigned short* dst = (qkv == 0) ? Q : K;
        float scale = (qkv == 0) ? 0.18033688011112042f : 1.0f;
        for (int m = 0; m < 4; m++)
            for (int n = 0; n < 4; n++) {
                int C = ncol0 + wc * 64 + n * 16 + r;
                int h = C >> 6, d = C & 63;
                float bb = bias[C];
                for (int reg = 0; reg < 4; reg++) {
                    int R = m0 + wr * 64 + m * 16 + 4 * g + reg;
                    int b = R >> 11, s = R & 2047;
                    float val = (acc[m][n][reg] + bb) * scale;
                    dst[((((size_t)b * 16 + h) * 2048) + s) * 64 + d] = f2bf(val);
                }
            }
    } else {
        unsigned short* T = (unsigned short*)smem;  // [128][136]
        for (int m = 0; m < 4; m++)
            for (int n = 0; n < 4; n++) {
                int Cl = wc * 64 + n * 16 + r;
                float bb = bv[ncol0 + Cl];
                for (int reg = 0; reg < 4; reg++) {
                    int Rl = wr * 64 + m * 16 + 4 * g + reg;
                    T[Rl * 136 + Cl] = f2bf(acc[m][n][reg] + bb);
                }
            }
        __syncthreads();
        int dl = tid >> 1, s0c = (tid & 1) * 64;
        int Cg = ncol0 + dl;
        int h = Cg >> 6, dd = Cg & 63;
        int bidx = m0 >> 11;
        int sbase = (m0 & 2047) + s0c;
        unsigned short* dstp = Vt + (((size_t)bidx * 16 + h) * 64 + dd) * 2048 + sbase;
        for (int jc = 0; jc < 8; jc++) {
            ushort8 v;
            for (int u = 0; u < 8; u++) v[u] = T[(s0c + jc * 8 + u) * 136 + dl];
            *(ushort8*)(dstp + jc * 8) = v;
        }
    }
}

// ---------------- pass 2: flash attention (R19 verbatim — verified 84.7 us) ------
// Staged K/V (KVBLK=64), joint-QK, no-max softmax, ones-MFMA denominator,
// per-qi PV with [16][64] P bounce, T2/G21 swizzles, XCD swizzle, T5 setprio,
// lb(256,4), 40 KiB LDS. Grid MUST be (16,64).
__global__ __launch_bounds__(256, 4) void attn(
    const unsigned short* __restrict__ Q, const unsigned short* __restrict__ K,
    const unsigned short* __restrict__ Vt, float* __restrict__ out) {
    // LDS: K 2x8K @0, V 2x8K @16K, P [4][16][64] ushort @32K  (total 40 KiB)
    __shared__ __align__(16) unsigned char lds[40960];

    int tid = threadIdx.x, w = tid >> 6, lane = tid & 63;
    int r = lane & 15, g = lane >> 4;
    // T1 XCD swizzle: 1024 blocks, 8 XCDs, 128 contiguous per XCD
    int f = blockIdx.x + (blockIdx.y << 4);
    int nf = ((f & 7) << 7) | (f >> 3);
    int qt = nf & 15, bh = nf >> 4;
    int q0 = qt * 128 + w * 32;
    const unsigned short* Qb = Q + (size_t)bh * 2048 * 64;
    const unsigned short* Kb = K + (size_t)bh * 2048 * 64;
    const unsigned short* Vb = Vt + (size_t)bh * 64 * 2048;

    // stage K tile [64 kv][64 d] and V tile [64 d][64 kv], pre-swizzled source
    auto stageKV = [&](int buf, int kv0) {
#pragma unroll
        for (int i = 0; i < 2; i++) {
            int slot = (i * 4 + w) * 64 + lane;
            int row = slot >> 3;
            int ch = (slot & 7) ^ (row & 7);
            gload_lds16(Kb + (size_t)(kv0 + row) * 64 + ch * 8,
                        lds + buf * 8192 + (i * 4 + w) * 1024);
            gload_lds16(Vb + (size_t)row * 2048 + kv0 + ch * 8,
                        lds + 16384 + buf * 8192 + (i * 4 + w) * 1024);
        }
    };

    // Q^T B-frags (loaded once from global)
    bf16x8 qf[2][2];
#pragma unroll
    for (int qi = 0; qi < 2; qi++)
#pragma unroll
        for (int sl = 0; sl < 2; sl++)
            qf[qi][sl] = *(const bf16x8*)(Qb + (size_t)(q0 + qi * 16 + r) * 64 + sl * 32 + g * 8);

    // all-ones A-frag for row-sum MFMA
    bf16x8 ones8;
#pragma unroll
    for (int i = 0; i < 8; i++) ones8[i] = (__bf16)1.0f;

    f32x4 o[2][4], ls[2];
#pragma unroll
    for (int qi = 0; qi < 2; qi++) {
#pragma unroll
        for (int u = 0; u < 4; u++) ls[qi][u] = 0.f;
#pragma unroll
        for (int d = 0; d < 4; d++)
#pragma unroll
            for (int u = 0; u < 4; u++) o[qi][d][u] = 0.f;
    }

    stageKV(0, 0);
    __syncthreads();
    int buf = 0;
    int rsw = (r & 7) << 4;  // read/write-side XOR (byte units)
    unsigned char* Pw = lds + 32768 + w * 2048;  // [16][64] ushort, swizzled

    for (int t = 0; t < 32; ++t) {
        if (t < 31) stageKV(buf ^ 1, (t + 1) * 64);
        const unsigned char* Kl = lds + buf * 8192;
        const unsigned char* Vl = lds + 16384 + buf * 8192;

        // ---- joint QK: S^T = K . Q^T for BOTH qi (K read once) ----
        f32x4 s[2][4];
#pragma unroll
        for (int qi = 0; qi < 2; qi++)
#pragma unroll
            for (int kvt = 0; kvt < 4; kvt++)
#pragma unroll
                for (int u = 0; u < 4; u++) s[qi][kvt][u] = 0.f;
        __builtin_amdgcn_s_setprio(1);
#pragma unroll
        for (int kvt = 0; kvt < 4; kvt++) {
            const unsigned char* kp = Kl + (kvt * 16 + r) * 128;
            bf16x8 k0 = *(const bf16x8*)(kp + ((g << 4) ^ rsw));
            bf16x8 k1 = *(const bf16x8*)(kp + (((4 + g) << 4) ^ rsw));
            s[0][kvt] = MFMA16(k0, qf[0][0], s[0][kvt]);
            s[0][kvt] = MFMA16(k1, qf[0][1], s[0][kvt]);
            s[1][kvt] = MFMA16(k0, qf[1][0], s[1][kvt]);
            s[1][kvt] = MFMA16(k1, qf[1][1], s[1][kvt]);
        }
        __builtin_amdgcn_s_setprio(0);

        // ---- per qi: exp2 (no max) + pack -> P, then PV + ones-MFMA ls ----
#pragma unroll
        for (int qi = 0; qi < 2; qi++) {
#pragma unroll
            for (int kvt = 0; kvt < 4; kvt++) {
                bf16x4 pw;
                pw[0] = (__bf16)__builtin_amdgcn_exp2f(s[qi][kvt][0]);
                pw[1] = (__bf16)__builtin_amdgcn_exp2f(s[qi][kvt][1]);
                pw[2] = (__bf16)__builtin_amdgcn_exp2f(s[qi][kvt][2]);
                pw[3] = (__bf16)__builtin_amdgcn_exp2f(s[qi][kvt][3]);
                *(bf16x4*)(Pw + (r << 7) + ((kvt * 32 + g * 8) ^ rsw)) = pw;
            }
            __builtin_amdgcn_s_setprio(1);
#pragma unroll
            for (int ks2 = 0; ks2 < 2; ks2++) {
                bf16x8 pf = *(const bf16x8*)(Pw + (r << 7) + ((ks2 * 64 + g * 16) ^ rsw));
                ls[qi] = MFMA16(ones8, pf, ls[qi]);
#pragma unroll
                for (int d = 0; d < 4; d++) {
                    bf16x8 vf = *(const bf16x8*)(Vl + (d * 16 + r) * 128 + (((ks2 * 4 + g) << 4) ^ rsw));
                    o[qi][d] = MFMA16(vf, pf, o[qi][d]);
                }
            }
            __builtin_amdgcn_s_setprio(0);
        }

        __syncthreads();   // drains vmcnt (next-tile stage) + lgkm; swap buffers
        buf ^= 1;
    }

    // ---- epilogue: O^T[d][q] / l -> out[b][s][h*64+d] ----
    int b = bh >> 4, h = bh & 15;
#pragma unroll
    for (int qi = 0; qi < 2; qi++) {
        float inv = 1.0f / ls[qi][0];
        float* ob = out + ((size_t)b * 2048 + q0 + qi * 16 + r) * 1024 + h * 64;
#pragma unroll
        for (int d = 0; d < 4; d++) {
            float4 v;
            v.x = o[qi][d][0] * inv; v.y = o[qi][d][1] * inv;
            v.z = o[qi][d][2] * inv; v.w = o[qi][d][3] * inv;
            *(float4*)(ob + d * 16 + 4 * g) = v;
        }
    }
}

extern "C" void kernel_launch(void* const* d_in, const int* in_sizes, int n_in,
                              void* d_out, int out_size, void* d_ws, size_t ws_size,
                              hipStream_t stream) {
    const float* X  = (const float*)d_in[0];
    const float* Wq = (const float*)d_in[1];
    const float* bq = (const float*)d_in[2];
    const float* Wk = (const float*)d_in[3];
    const float* bk = (const float*)d_in[4];
    const float* Wv = (const float*)d_in[5];
    const float* bv = (const float*)d_in[6];
    float* out = (float*)d_out;
    char* ws = (char*)d_ws;

    unsigned short* Xb  = (unsigned short*)(ws);
    unsigned short* Wt  = (unsigned short*)(ws + 16777216);
    unsigned short* Qw  = (unsigned short*)(ws + 23068672);
    unsigned short* Kw  = (unsigned short*)(ws + 39845888);
    unsigned short* Vtw = (unsigned short*)(ws + 56623104);

    hipLaunchKernelGGL(convert_x, dim3(4096), dim3(256), 0, stream, X, Xb);
    hipLaunchKernelGGL(wtrans, dim3(16, 16, 3), dim3(256), 0, stream, Wq, Wk, Wv, Wt);
    hipLaunchKernelGGL(qkv_gemm, dim3(24, 64), dim3(256), 0, stream,
                       Xb, Wt, bq, bk, bv, Qw, Kw, Vtw);
    hipLaunchKernelGGL(attn, dim3(16, 64), dim3(256), 0, stream, Qw, Kw, Vtw, out);
}